// Round 2
// baseline (670.132 us; speedup 1.0000x reference)
//
#include <hip/hip_runtime.h>
#include <hip/hip_bf16.h>

#define D 256

typedef __attribute__((ext_vector_type(8))) short short8;
typedef __attribute__((ext_vector_type(4))) float floatx4;

static __device__ __forceinline__ unsigned short f2bf(float f) {
  unsigned int u = __builtin_bit_cast(unsigned int, f);
  u += 0x7FFFu + ((u >> 16) & 1u);   // round-to-nearest-even to bf16
  return (unsigned short)(u >> 16);
}

// ---- detect int64 vs int32 edge_index storage --------------------------
// int64 little-endian with values < 2^31: every odd int32 word is 0.
// int32: odd words are random row indices; P(32 consecutive all 0) ~ 0.
__global__ void detect_kernel(const int* __restrict__ ei32, int* __restrict__ flag) {
  int any = 0;
  for (int i = 0; i < 32; ++i) any |= ei32[2 * i + 1];
  *flag = (any == 0) ? 1 : 0;   // 1 => int64 layout
}

static __device__ __forceinline__ int edge_at(const void* ei, int is64, long long idx) {
  return is64 ? (int)((const long long*)ei)[idx] : ((const int*)ei)[idx];
}

// ---- CSR build ---------------------------------------------------------
__global__ void count_kernel(const void* __restrict__ ei, const int* __restrict__ flag,
                             int* __restrict__ counts, int E, int N) {
  int is64 = *flag;
  int e = blockIdx.x * blockDim.x + threadIdx.x;
  if (e < E) {
    int c = edge_at(ei, is64, (long long)E + e);
    if ((unsigned)c < (unsigned)N) atomicAdd(&counts[c], 1);
  }
}

__global__ void scan_kernel(const int* __restrict__ counts, int* __restrict__ offsets, int n) {
  __shared__ int part[1024];
  int t = threadIdx.x;
  int CH = (n + 1023) / 1024;
  int lo = t * CH;
  int hi = lo + CH; if (hi > n) hi = n;
  int s = 0;
  for (int i = lo; i < hi; ++i) s += counts[i];
  part[t] = s;
  __syncthreads();
  for (int d = 1; d < 1024; d <<= 1) {
    int v = (t >= d) ? part[t - d] : 0;
    __syncthreads();
    part[t] += v;
    __syncthreads();
  }
  int run = (t == 0) ? 0 : part[t - 1];
  for (int i = lo; i < hi; ++i) { offsets[i] = run; run += counts[i]; }
  if (hi == n) offsets[n] = run;  // all tail threads hold run == total
}

__global__ void fill_kernel(const void* __restrict__ ei, const int* __restrict__ flag,
                            const int* __restrict__ offsets, int* __restrict__ cursor,
                            int* __restrict__ edge_src, int E, int N) {
  int is64 = *flag;
  int e = blockIdx.x * blockDim.x + threadIdx.x;
  if (e < E) {
    int c = edge_at(ei, is64, (long long)E + e);
    int s = edge_at(ei, is64, (long long)e);
    if ((unsigned)c < (unsigned)N && (unsigned)s < (unsigned)N) {
      int pos = atomicAdd(&cursor[c], 1);
      edge_src[offsets[c] + pos] = s;
    }
  }
}

// ---- W transpose + bf16 convert: Wt[oc][k] (k<256 -> W_l, else W_r) ----
__global__ void wt_kernel(const float* __restrict__ Wl, const float* __restrict__ Wr,
                          unsigned short* __restrict__ Wt) {
  int idx = blockIdx.x * blockDim.x + threadIdx.x;  // 0 .. 256*512-1
  int oc = idx >> 9, k = idx & 511;
  float v = (k < 256) ? Wl[k * 256 + oc] : Wr[(k - 256) * 256 + oc];
  Wt[idx] = f2bf(v);
}

// ---- scatter-mean via CSR: one block per target node, f32 out ----------
__global__ void aggr_kernel(const float* __restrict__ xsrc, const int* __restrict__ offsets,
                            const int* __restrict__ edge_src, float* __restrict__ aggr) {
  int node = blockIdx.x;
  int t = threadIdx.x;                  // feature 0..255
  int start = offsets[node], end = offsets[node + 1];
  float acc = 0.f;
  int i = start;
  for (; i + 4 <= end; i += 4) {
    int s0 = edge_src[i], s1 = edge_src[i + 1], s2 = edge_src[i + 2], s3 = edge_src[i + 3];
    acc += xsrc[(size_t)s0 * D + t];
    acc += xsrc[(size_t)s1 * D + t];
    acc += xsrc[(size_t)s2 * D + t];
    acc += xsrc[(size_t)s3 * D + t];
  }
  for (; i < end; ++i) acc += xsrc[(size_t)edge_src[i] * D + t];
  int deg = end - start;
  aggr[(size_t)node * D + t] = acc / (float)(deg > 0 ? deg : 1);
}

// ---- fused GEMM: out[64 nodes][256] = [aggr|x_tgt]bf16 @ Wcat + b ------
// aggr lives in d_out (f32); each block reads its own 64 rows into LDS
// before overwriting them. A_lds[64][512] bf16 (64KB), XOR-swizzled in
// 16B chunks: chunk' = chunk ^ (row&7) within each 32-chunk half.
__global__ __launch_bounds__(256) void gemm_kernel(const float* __restrict__ aggr,
                                                   const float* __restrict__ xtgt,
                                                   const unsigned short* __restrict__ Wt,
                                                   const float* __restrict__ bias,
                                                   float* __restrict__ out, int n_tgt) {
  __shared__ __align__(16) unsigned short A_lds[64 * 512];
  int t = threadIdx.x;
  int mbase = blockIdx.x * 64;

  // stage aggr (f32 -> bf16) -> A_lds rows, k=0..255
#pragma unroll
  for (int it = 0; it < 8; ++it) {
    int chunk = it * 256 + t;           // 0..2047
    int r = chunk >> 5, c = chunk & 31; // c = 8-elem k-group
    int node = mbase + r;
    floatx4 f0 = {0.f, 0.f, 0.f, 0.f}, f1 = {0.f, 0.f, 0.f, 0.f};
    if (node < n_tgt) {
      f0 = *(const floatx4*)&aggr[(size_t)node * D + c * 8];
      f1 = *(const floatx4*)&aggr[(size_t)node * D + c * 8 + 4];
    }
    short8 v;
    v[0] = (short)f2bf(f0[0]); v[1] = (short)f2bf(f0[1]);
    v[2] = (short)f2bf(f0[2]); v[3] = (short)f2bf(f0[3]);
    v[4] = (short)f2bf(f1[0]); v[5] = (short)f2bf(f1[1]);
    v[6] = (short)f2bf(f1[2]); v[7] = (short)f2bf(f1[3]);
    int sc = c ^ (r & 7);
    *(short8*)&A_lds[r * 512 + sc * 8] = v;
  }
  // stage x_tgt (f32 -> bf16) -> A_lds rows, k=256..511
#pragma unroll
  for (int it = 0; it < 8; ++it) {
    int chunk = it * 256 + t;
    int r = chunk >> 5, c = chunk & 31;
    int node = mbase + r;
    floatx4 f0 = {0.f, 0.f, 0.f, 0.f}, f1 = {0.f, 0.f, 0.f, 0.f};
    if (node < n_tgt) {
      f0 = *(const floatx4*)&xtgt[(size_t)node * D + c * 8];
      f1 = *(const floatx4*)&xtgt[(size_t)node * D + c * 8 + 4];
    }
    short8 v;
    v[0] = (short)f2bf(f0[0]); v[1] = (short)f2bf(f0[1]);
    v[2] = (short)f2bf(f0[2]); v[3] = (short)f2bf(f0[3]);
    v[4] = (short)f2bf(f1[0]); v[5] = (short)f2bf(f1[1]);
    v[6] = (short)f2bf(f1[2]); v[7] = (short)f2bf(f1[3]);
    int sc = (32 + c) ^ (r & 7);
    *(short8*)&A_lds[r * 512 + sc * 8] = v;
  }
  __syncthreads();

  int lane = t & 63, w = t >> 6;
  int lr = lane & 15, lq = lane >> 4;

  floatx4 acc[4][4];
#pragma unroll
  for (int mt = 0; mt < 4; ++mt)
#pragma unroll
    for (int nt = 0; nt < 4; ++nt) acc[mt][nt] = (floatx4){0.f, 0.f, 0.f, 0.f};

  const unsigned short* WtW = Wt + ((size_t)(64 * w + lr)) * 512 + lq * 8;

#pragma unroll
  for (int ks = 0; ks < 16; ++ks) {
    short8 a[4], b[4];
#pragma unroll
    for (int mt = 0; mt < 4; ++mt) {
      int row = 16 * mt + lr;
      int chunk = (ks * 4 + lq) ^ (row & 7);
      a[mt] = *(const short8*)&A_lds[row * 512 + chunk * 8];
    }
#pragma unroll
    for (int nt = 0; nt < 4; ++nt)
      b[nt] = *(const short8*)&WtW[(size_t)nt * 16 * 512 + ks * 32];
#pragma unroll
    for (int mt = 0; mt < 4; ++mt)
#pragma unroll
      for (int nt = 0; nt < 4; ++nt)
        acc[mt][nt] = __builtin_amdgcn_mfma_f32_16x16x32_bf16(a[mt], b[nt], acc[mt][nt], 0, 0, 0);
  }

  // epilogue: D frag -> out. row=(lane>>4)*4+reg, col=lane&15
#pragma unroll
  for (int nt = 0; nt < 4; ++nt) {
    int oc = 64 * w + 16 * nt + lr;
    float bv = bias[oc];
#pragma unroll
    for (int mt = 0; mt < 4; ++mt) {
#pragma unroll
      for (int r4 = 0; r4 < 4; ++r4) {
        int node = mbase + 16 * mt + lq * 4 + r4;
        if (node < n_tgt) out[(size_t)node * D + oc] = acc[mt][nt][r4] + bv;
      }
    }
  }
}

extern "C" void kernel_launch(void* const* d_in, const int* in_sizes, int n_in,
                              void* d_out, int out_size, void* d_ws, size_t ws_size,
                              hipStream_t stream) {
  const float* x_src = (const float*)d_in[0];
  const float* x_tgt = (const float*)d_in[1];
  const void* ei = d_in[2];
  const float* W_l = (const float*)d_in[3];
  const float* b_l = (const float*)d_in[4];
  const float* W_r = (const float*)d_in[5];
  float* out = (float*)d_out;

  const int N_t = in_sizes[1] / D;     // 100000 target nodes
  const int E = in_sizes[2] / 2;       // 1600000 edges

  char* ws = (char*)d_ws;
  size_t o = 0;
  auto alloc = [&](size_t bytes) { size_t cur = o; o = (o + bytes + 255) & ~(size_t)255; return cur; };
  int* flag              = (int*)(ws + alloc(4));
  int* counts            = (int*)(ws + alloc((size_t)N_t * 4));
  int* offsets           = (int*)(ws + alloc(((size_t)N_t + 1) * 4));
  int* cursor            = (int*)(ws + alloc((size_t)N_t * 4));
  size_t zero_end        = o;                       // memset everything above
  int* edge_src          = (int*)(ws + alloc((size_t)E * 4));
  unsigned short* Wt     = (unsigned short*)(ws + alloc((size_t)256 * 512 * 2));
  // total ws use: ~7.9 MB

  hipMemsetAsync(ws, 0, zero_end, stream);

  int eb = (E + 255) / 256;
  detect_kernel<<<1, 1, 0, stream>>>((const int*)ei, flag);
  count_kernel<<<eb, 256, 0, stream>>>(ei, flag, counts, E, N_t);
  scan_kernel<<<1, 1024, 0, stream>>>(counts, offsets, N_t);
  fill_kernel<<<eb, 256, 0, stream>>>(ei, flag, offsets, cursor, edge_src, E, N_t);
  wt_kernel<<<512, 256, 0, stream>>>(W_l, W_r, Wt);
  // aggr (f32) lives in d_out; gemm reads+overwrites its own rows
  aggr_kernel<<<N_t, 256, 0, stream>>>(x_src, offsets, edge_src, out);
  gemm_kernel<<<(N_t + 63) / 64, 256, 0, stream>>>(out, x_tgt, Wt, b_l, out, N_t);
}

// Round 3
// 592.456 us; speedup vs baseline: 1.1311x; 1.1311x over previous
//
#include <hip/hip_runtime.h>
#include <hip/hip_bf16.h>

#define D 256

typedef __attribute__((ext_vector_type(8))) short short8;
typedef __attribute__((ext_vector_type(4))) short short4v;
typedef __attribute__((ext_vector_type(4))) float floatx4;

static __device__ __forceinline__ unsigned short f2bf(float f) {
  unsigned int u = __builtin_bit_cast(unsigned int, f);
  u += 0x7FFFu + ((u >> 16) & 1u);   // RNE to bf16
  return (unsigned short)(u >> 16);
}
static __device__ __forceinline__ float bf2f(unsigned short s) {
  unsigned int u = ((unsigned int)s) << 16;
  return __builtin_bit_cast(float, u);
}

// ---- detect int64 vs int32 edge_index storage --------------------------
__global__ void detect_kernel(const int* __restrict__ ei32, int* __restrict__ flag) {
  int any = 0;
  for (int i = 0; i < 32; ++i) any |= ei32[2 * i + 1];
  *flag = (any == 0) ? 1 : 0;   // 1 => int64 layout
}

static __device__ __forceinline__ int edge_at(const void* ei, int is64, long long idx) {
  return is64 ? (int)((const long long*)ei)[idx] : ((const int*)ei)[idx];
}

// ---- CSR build ---------------------------------------------------------
__global__ void count_kernel(const void* __restrict__ ei, const int* __restrict__ flag,
                             int* __restrict__ counts, int E, int N) {
  int is64 = *flag;
  int e = blockIdx.x * blockDim.x + threadIdx.x;
  if (e < E) {
    int c = edge_at(ei, is64, (long long)E + e);
    if ((unsigned)c < (unsigned)N) atomicAdd(&counts[c], 1);
  }
}

__global__ void scan_kernel(const int* __restrict__ counts, int* __restrict__ offsets, int n) {
  __shared__ int part[1024];
  int t = threadIdx.x;
  int CH = (n + 1023) / 1024;
  int lo = t * CH;
  int hi = lo + CH; if (hi > n) hi = n;
  int s = 0;
  for (int i = lo; i < hi; ++i) s += counts[i];
  part[t] = s;
  __syncthreads();
  for (int d = 1; d < 1024; d <<= 1) {
    int v = (t >= d) ? part[t - d] : 0;
    __syncthreads();
    part[t] += v;
    __syncthreads();
  }
  int run = (t == 0) ? 0 : part[t - 1];
  for (int i = lo; i < hi; ++i) { offsets[i] = run; run += counts[i]; }
  if (hi == n) offsets[n] = run;
}

__global__ void fill_kernel(const void* __restrict__ ei, const int* __restrict__ flag,
                            const int* __restrict__ offsets, int* __restrict__ cursor,
                            int* __restrict__ edge_src, int E, int N) {
  int is64 = *flag;
  int e = blockIdx.x * blockDim.x + threadIdx.x;
  if (e < E) {
    int c = edge_at(ei, is64, (long long)E + e);
    int s = edge_at(ei, is64, (long long)e);
    if ((unsigned)c < (unsigned)N && (unsigned)s < (unsigned)N) {
      int pos = atomicAdd(&cursor[c], 1);
      edge_src[offsets[c] + pos] = s;
    }
  }
}

// ---- W transpose + bf16: Wt[oc][k] (k<256 -> W_l, else W_r) ------------
__global__ void wt_kernel(const float* __restrict__ Wl, const float* __restrict__ Wr,
                          unsigned short* __restrict__ Wt) {
  int idx = blockIdx.x * blockDim.x + threadIdx.x;
  int oc = idx >> 9, k = idx & 511;
  float v = (k < 256) ? Wl[k * 256 + oc] : Wr[(k - 256) * 256 + oc];
  Wt[idx] = f2bf(v);
}

// ---- x_src f32 -> bf16 (8 elems/thread) --------------------------------
__global__ void xcast_kernel(const float* __restrict__ x, unsigned short* __restrict__ xb,
                             long long n8) {
  long long i = (long long)blockIdx.x * blockDim.x + threadIdx.x;
  if (i >= n8) return;
  floatx4 f0 = *(const floatx4*)&x[i * 8];
  floatx4 f1 = *(const floatx4*)&x[i * 8 + 4];
  short8 v;
  v[0] = (short)f2bf(f0[0]); v[1] = (short)f2bf(f0[1]);
  v[2] = (short)f2bf(f0[2]); v[3] = (short)f2bf(f0[3]);
  v[4] = (short)f2bf(f1[0]); v[5] = (short)f2bf(f1[1]);
  v[6] = (short)f2bf(f1[2]); v[7] = (short)f2bf(f1[3]);
  *(short8*)&xb[i * 8] = v;
}

// ---- scatter-mean via CSR, bf16 in / bf16 out, 1 wave per node ---------
__global__ __launch_bounds__(64) void aggr_bf_kernel(const unsigned short* __restrict__ xsb,
                                                     const int* __restrict__ offsets,
                                                     const int* __restrict__ edge_src,
                                                     unsigned short* __restrict__ aggr) {
  int node = blockIdx.x;
  int t = threadIdx.x;                  // feature group: 4t..4t+3
  int start = offsets[node], end = offsets[node + 1];
  float a0 = 0.f, a1 = 0.f, a2 = 0.f, a3 = 0.f;
  int i = start;
  for (; i + 4 <= end; i += 4) {
    int s0 = edge_src[i], s1 = edge_src[i + 1], s2 = edge_src[i + 2], s3 = edge_src[i + 3];
    short4v v0 = *(const short4v*)&xsb[(size_t)s0 * D + t * 4];
    short4v v1 = *(const short4v*)&xsb[(size_t)s1 * D + t * 4];
    short4v v2 = *(const short4v*)&xsb[(size_t)s2 * D + t * 4];
    short4v v3 = *(const short4v*)&xsb[(size_t)s3 * D + t * 4];
    a0 += bf2f((unsigned short)v0[0]) + bf2f((unsigned short)v1[0]) + bf2f((unsigned short)v2[0]) + bf2f((unsigned short)v3[0]);
    a1 += bf2f((unsigned short)v0[1]) + bf2f((unsigned short)v1[1]) + bf2f((unsigned short)v2[1]) + bf2f((unsigned short)v3[1]);
    a2 += bf2f((unsigned short)v0[2]) + bf2f((unsigned short)v1[2]) + bf2f((unsigned short)v2[2]) + bf2f((unsigned short)v3[2]);
    a3 += bf2f((unsigned short)v0[3]) + bf2f((unsigned short)v1[3]) + bf2f((unsigned short)v2[3]) + bf2f((unsigned short)v3[3]);
  }
  for (; i < end; ++i) {
    short4v v = *(const short4v*)&xsb[(size_t)edge_src[i] * D + t * 4];
    a0 += bf2f((unsigned short)v[0]); a1 += bf2f((unsigned short)v[1]);
    a2 += bf2f((unsigned short)v[2]); a3 += bf2f((unsigned short)v[3]);
  }
  int deg = end - start;
  float inv = 1.f / (float)(deg > 0 ? deg : 1);
  short4v r;
  r[0] = (short)f2bf(a0 * inv); r[1] = (short)f2bf(a1 * inv);
  r[2] = (short)f2bf(a2 * inv); r[3] = (short)f2bf(a3 * inv);
  *(short4v*)&aggr[(size_t)node * D + t * 4] = r;
}

// ---- f32 fallback aggr (aggr lives in d_out) ----------------------------
__global__ void aggr_f32_kernel(const float* __restrict__ xsrc, const int* __restrict__ offsets,
                                const int* __restrict__ edge_src, float* __restrict__ aggr) {
  int node = blockIdx.x;
  int t = threadIdx.x;
  int start = offsets[node], end = offsets[node + 1];
  float acc = 0.f;
  int i = start;
  for (; i + 4 <= end; i += 4) {
    int s0 = edge_src[i], s1 = edge_src[i + 1], s2 = edge_src[i + 2], s3 = edge_src[i + 3];
    acc += xsrc[(size_t)s0 * D + t];
    acc += xsrc[(size_t)s1 * D + t];
    acc += xsrc[(size_t)s2 * D + t];
    acc += xsrc[(size_t)s3 * D + t];
  }
  for (; i < end; ++i) acc += xsrc[(size_t)edge_src[i] * D + t];
  int deg = end - start;
  aggr[(size_t)node * D + t] = acc / (float)(deg > 0 ? deg : 1);
}

// ---- fused GEMM: out[64][256] = [aggr|x_tgt]bf16 @ Wcat + b -------------
// A_lds[64][512] bf16 (64KB), XOR-swizzled 16B chunks: chunk' = chunk ^ (row&7)
template <bool AGGR_BF16>
__global__ __launch_bounds__(256) void gemm_kernel(const void* __restrict__ aggrp,
                                                   const float* __restrict__ xtgt,
                                                   const unsigned short* __restrict__ Wt,
                                                   const float* __restrict__ bias,
                                                   float* __restrict__ out, int n_tgt) {
  __shared__ __align__(16) unsigned short A_lds[64 * 512];
  int t = threadIdx.x;
  int mbase = blockIdx.x * 64;

  // stage aggr -> A_lds rows, k=0..255
#pragma unroll
  for (int it = 0; it < 8; ++it) {
    int chunk = it * 256 + t;           // 0..2047
    int r = chunk >> 5, c = chunk & 31;
    int node = mbase + r;
    short8 v = {0, 0, 0, 0, 0, 0, 0, 0};
    if (node < n_tgt) {
      if (AGGR_BF16) {
        v = *(const short8*)&((const unsigned short*)aggrp)[(size_t)node * D + c * 8];
      } else {
        const float* ap = (const float*)aggrp;
        floatx4 f0 = *(const floatx4*)&ap[(size_t)node * D + c * 8];
        floatx4 f1 = *(const floatx4*)&ap[(size_t)node * D + c * 8 + 4];
        v[0] = (short)f2bf(f0[0]); v[1] = (short)f2bf(f0[1]);
        v[2] = (short)f2bf(f0[2]); v[3] = (short)f2bf(f0[3]);
        v[4] = (short)f2bf(f1[0]); v[5] = (short)f2bf(f1[1]);
        v[6] = (short)f2bf(f1[2]); v[7] = (short)f2bf(f1[3]);
      }
    }
    int sc = c ^ (r & 7);
    *(short8*)&A_lds[r * 512 + sc * 8] = v;
  }
  // stage x_tgt (f32 -> bf16) -> A_lds rows, k=256..511
#pragma unroll
  for (int it = 0; it < 8; ++it) {
    int chunk = it * 256 + t;
    int r = chunk >> 5, c = chunk & 31;
    int node = mbase + r;
    floatx4 f0 = {0.f, 0.f, 0.f, 0.f}, f1 = {0.f, 0.f, 0.f, 0.f};
    if (node < n_tgt) {
      f0 = *(const floatx4*)&xtgt[(size_t)node * D + c * 8];
      f1 = *(const floatx4*)&xtgt[(size_t)node * D + c * 8 + 4];
    }
    short8 v;
    v[0] = (short)f2bf(f0[0]); v[1] = (short)f2bf(f0[1]);
    v[2] = (short)f2bf(f0[2]); v[3] = (short)f2bf(f0[3]);
    v[4] = (short)f2bf(f1[0]); v[5] = (short)f2bf(f1[1]);
    v[6] = (short)f2bf(f1[2]); v[7] = (short)f2bf(f1[3]);
    int sc = (32 + c) ^ (r & 7);
    *(short8*)&A_lds[r * 512 + sc * 8] = v;
  }
  __syncthreads();

  int lane = t & 63, w = t >> 6;
  int lr = lane & 15, lq = lane >> 4;

  floatx4 acc[4][4];
#pragma unroll
  for (int mt = 0; mt < 4; ++mt)
#pragma unroll
    for (int nt = 0; nt < 4; ++nt) acc[mt][nt] = (floatx4){0.f, 0.f, 0.f, 0.f};

  const unsigned short* WtW = Wt + ((size_t)(64 * w + lr)) * 512 + lq * 8;

#pragma unroll
  for (int ks = 0; ks < 16; ++ks) {
    short8 a[4], b[4];
#pragma unroll
    for (int mt = 0; mt < 4; ++mt) {
      int row = 16 * mt + lr;
      int chunk = (ks * 4 + lq) ^ (row & 7);
      a[mt] = *(const short8*)&A_lds[row * 512 + chunk * 8];
    }
#pragma unroll
    for (int nt = 0; nt < 4; ++nt)
      b[nt] = *(const short8*)&WtW[(size_t)nt * 16 * 512 + ks * 32];
#pragma unroll
    for (int mt = 0; mt < 4; ++mt)
#pragma unroll
      for (int nt = 0; nt < 4; ++nt)
        acc[mt][nt] = __builtin_amdgcn_mfma_f32_16x16x32_bf16(a[mt], b[nt], acc[mt][nt], 0, 0, 0);
  }

  // epilogue: row=(lane>>4)*4+reg, col=lane&15
#pragma unroll
  for (int nt = 0; nt < 4; ++nt) {
    int oc = 64 * w + 16 * nt + lr;
    float bv = bias[oc];
#pragma unroll
    for (int mt = 0; mt < 4; ++mt) {
#pragma unroll
      for (int r4 = 0; r4 < 4; ++r4) {
        int node = mbase + 16 * mt + lq * 4 + r4;
        if (node < n_tgt) out[(size_t)node * D + oc] = acc[mt][nt][r4] + bv;
      }
    }
  }
}

extern "C" void kernel_launch(void* const* d_in, const int* in_sizes, int n_in,
                              void* d_out, int out_size, void* d_ws, size_t ws_size,
                              hipStream_t stream) {
  const float* x_src = (const float*)d_in[0];
  const float* x_tgt = (const float*)d_in[1];
  const void* ei = d_in[2];
  const float* W_l = (const float*)d_in[3];
  const float* b_l = (const float*)d_in[4];
  const float* W_r = (const float*)d_in[5];
  float* out = (float*)d_out;

  const int N_s = in_sizes[0] / D;     // source nodes
  const int N_t = in_sizes[1] / D;     // target nodes
  const int E = in_sizes[2] / 2;       // edges

  char* ws = (char*)d_ws;
  size_t o = 0;
  auto alloc = [&](size_t bytes) { size_t cur = o; o = (o + bytes + 255) & ~(size_t)255; return cur; };
  int* flag              = (int*)(ws + alloc(4));
  int* counts            = (int*)(ws + alloc((size_t)N_t * 4));
  int* offsets           = (int*)(ws + alloc(((size_t)N_t + 1) * 4));
  int* cursor            = (int*)(ws + alloc((size_t)N_t * 4));
  size_t zero_end        = o;
  int* edge_src          = (int*)(ws + alloc((size_t)E * 4));
  unsigned short* Wt     = (unsigned short*)(ws + alloc((size_t)256 * 512 * 2));
  size_t base_end        = o;
  unsigned short* xsrc_b = (unsigned short*)(ws + alloc((size_t)N_s * D * 2));
  unsigned short* aggr_b = (unsigned short*)(ws + alloc((size_t)N_t * D * 2));
  size_t bf16_end        = o;

  bool bf16_path = (ws_size >= bf16_end);
  (void)base_end;

  hipMemsetAsync(ws, 0, zero_end, stream);

  int eb = (E + 255) / 256;
  detect_kernel<<<1, 1, 0, stream>>>((const int*)ei, flag);
  count_kernel<<<eb, 256, 0, stream>>>(ei, flag, counts, E, N_t);
  scan_kernel<<<1, 1024, 0, stream>>>(counts, offsets, N_t);
  fill_kernel<<<eb, 256, 0, stream>>>(ei, flag, offsets, cursor, edge_src, E, N_t);
  wt_kernel<<<512, 256, 0, stream>>>(W_l, W_r, Wt);

  if (bf16_path) {
    long long n8 = (long long)N_s * D / 8;
    xcast_kernel<<<(int)((n8 + 255) / 256), 256, 0, stream>>>(x_src, xsrc_b, n8);
    aggr_bf_kernel<<<N_t, 64, 0, stream>>>(xsrc_b, offsets, edge_src, aggr_b);
    gemm_kernel<true><<<(N_t + 63) / 64, 256, 0, stream>>>(aggr_b, x_tgt, Wt, b_l, out, N_t);
  } else {
    aggr_f32_kernel<<<N_t, 256, 0, stream>>>(x_src, offsets, edge_src, out);
    gemm_kernel<false><<<(N_t + 63) / 64, 256, 0, stream>>>(out, x_tgt, Wt, b_l, out, N_t);
  }
}

// Round 4
// 432.190 us; speedup vs baseline: 1.5505x; 1.3708x over previous
//
#include <hip/hip_runtime.h>
#include <hip/hip_bf16.h>

#define D 256

typedef __attribute__((ext_vector_type(8))) short short8;
typedef __attribute__((ext_vector_type(4))) short short4v;
typedef __attribute__((ext_vector_type(4))) float floatx4;
typedef __attribute__((ext_vector_type(4))) int intx4;

static __device__ __forceinline__ unsigned short f2bf(float f) {
  unsigned int u = __builtin_bit_cast(unsigned int, f);
  u += 0x7FFFu + ((u >> 16) & 1u);   // RNE to bf16
  return (unsigned short)(u >> 16);
}
static __device__ __forceinline__ float bf2f(unsigned short s) {
  unsigned int u = ((unsigned int)s) << 16;
  return __builtin_bit_cast(float, u);
}

// ---- detect int64 vs int32 edge_index storage (one wave) ---------------
__global__ void detect_kernel(const int* __restrict__ ei32, int* __restrict__ flag) {
  int lane = threadIdx.x;
  int v = ei32[2 * lane + 1];
  unsigned long long nz = __ballot(v != 0);
  if (lane == 0) *flag = (nz == 0ULL) ? 1 : 0;   // 1 => int64 layout
}

static __device__ __forceinline__ int edge_at(const void* ei, int is64, long long idx) {
  return is64 ? (int)((const long long*)ei)[idx] : ((const int*)ei)[idx];
}

// ---- CSR build ---------------------------------------------------------
__global__ void count_kernel(const void* __restrict__ ei, const int* __restrict__ flag,
                             int* __restrict__ counts, int E, int N) {
  int is64 = *flag;
  int e = blockIdx.x * blockDim.x + threadIdx.x;
  if (e < E) {
    int c = edge_at(ei, is64, (long long)E + e);
    if ((unsigned)c < (unsigned)N) atomicAdd(&counts[c], 1);
  }
}

// phase A: per-block (1024-elem chunk) reduce
__global__ __launch_bounds__(256) void scan_blocksum_kernel(const int* __restrict__ counts,
                                                            int* __restrict__ bsum, int n) {
  __shared__ int sh[256];
  int b = blockIdx.x, t = threadIdx.x;
  int base = b * 1024 + t * 4;
  int s = 0;
  if (base + 3 < n) {
    intx4 v = *(const intx4*)&counts[base];
    s = v[0] + v[1] + v[2] + v[3];
  } else {
    for (int j = 0; j < 4; ++j) if (base + j < n) s += counts[base + j];
  }
  sh[t] = s;
  __syncthreads();
  for (int d = 128; d > 0; d >>= 1) {
    if (t < d) sh[t] += sh[t + d];
    __syncthreads();
  }
  if (t == 0) bsum[b] = sh[0];
}

// phase B: scan the (small) block-sum array; out[i]=exclusive, out[n]=total
__global__ void scan_kernel(const int* __restrict__ counts, int* __restrict__ offsets, int n) {
  __shared__ int part[1024];
  int t = threadIdx.x;
  int CH = (n + 1023) / 1024;
  int lo = t * CH;
  int hi = lo + CH; if (hi > n) hi = n;
  int s = 0;
  for (int i = lo; i < hi; ++i) s += counts[i];
  part[t] = s;
  __syncthreads();
  for (int d = 1; d < 1024; d <<= 1) {
    int v = (t >= d) ? part[t - d] : 0;
    __syncthreads();
    part[t] += v;
    __syncthreads();
  }
  int run = (t == 0) ? 0 : part[t - 1];
  for (int i = lo; i < hi; ++i) { offsets[i] = run; run += counts[i]; }
  if (hi == n) offsets[n] = run;
}

// phase C: chunk-local exclusive scan + block offset
__global__ __launch_bounds__(256) void scan_apply_kernel(const int* __restrict__ counts,
                                                         const int* __restrict__ boff,
                                                         int* __restrict__ offsets, int n) {
  __shared__ int sh[256];
  int b = blockIdx.x, t = threadIdx.x;
  int base = b * 1024 + t * 4;
  int c0 = (base + 0 < n) ? counts[base + 0] : 0;
  int c1 = (base + 1 < n) ? counts[base + 1] : 0;
  int c2 = (base + 2 < n) ? counts[base + 2] : 0;
  int c3 = (base + 3 < n) ? counts[base + 3] : 0;
  sh[t] = c0 + c1 + c2 + c3;
  __syncthreads();
  for (int d = 1; d < 256; d <<= 1) {
    int v = (t >= d) ? sh[t - d] : 0;
    __syncthreads();
    sh[t] += v;
    __syncthreads();
  }
  int excl = (t == 0 ? 0 : sh[t - 1]) + boff[b];
  if (base + 0 < n) offsets[base + 0] = excl;
  if (base + 1 < n) offsets[base + 1] = excl + c0;
  if (base + 2 < n) offsets[base + 2] = excl + c0 + c1;
  if (base + 3 < n) offsets[base + 3] = excl + c0 + c1 + c2;
  if (b == (int)gridDim.x - 1 && t == 255) offsets[n] = boff[gridDim.x];
}

__global__ void fill_kernel(const void* __restrict__ ei, const int* __restrict__ flag,
                            const int* __restrict__ offsets, int* __restrict__ cursor,
                            int* __restrict__ edge_src, int E, int N) {
  int is64 = *flag;
  int e = blockIdx.x * blockDim.x + threadIdx.x;
  if (e < E) {
    int c = edge_at(ei, is64, (long long)E + e);
    int s = edge_at(ei, is64, (long long)e);
    if ((unsigned)c < (unsigned)N && (unsigned)s < (unsigned)N) {
      int pos = atomicAdd(&cursor[c], 1);
      edge_src[offsets[c] + pos] = s;
    }
  }
}

// ---- W transpose + bf16: Wt[oc][k] (k<256 -> W_l, else W_r) ------------
__global__ void wt_kernel(const float* __restrict__ Wl, const float* __restrict__ Wr,
                          unsigned short* __restrict__ Wt) {
  int idx = blockIdx.x * blockDim.x + threadIdx.x;
  int oc = idx >> 9, k = idx & 511;
  float v = (k < 256) ? Wl[k * 256 + oc] : Wr[(k - 256) * 256 + oc];
  Wt[idx] = f2bf(v);
}

// ---- x_src f32 -> bf16 (8 elems/thread) --------------------------------
__global__ void xcast_kernel(const float* __restrict__ x, unsigned short* __restrict__ xb,
                             long long n8) {
  long long i = (long long)blockIdx.x * blockDim.x + threadIdx.x;
  if (i >= n8) return;
  floatx4 f0 = *(const floatx4*)&x[i * 8];
  floatx4 f1 = *(const floatx4*)&x[i * 8 + 4];
  short8 v;
  v[0] = (short)f2bf(f0[0]); v[1] = (short)f2bf(f0[1]);
  v[2] = (short)f2bf(f0[2]); v[3] = (short)f2bf(f0[3]);
  v[4] = (short)f2bf(f1[0]); v[5] = (short)f2bf(f1[1]);
  v[6] = (short)f2bf(f1[2]); v[7] = (short)f2bf(f1[3]);
  *(short8*)&xb[i * 8] = v;
}

// ---- scatter-mean via CSR, bf16 in / bf16 out, 1 wave per node ---------
__global__ __launch_bounds__(64) void aggr_bf_kernel(const unsigned short* __restrict__ xsb,
                                                     const int* __restrict__ offsets,
                                                     const int* __restrict__ edge_src,
                                                     unsigned short* __restrict__ aggr) {
  int node = blockIdx.x;
  int t = threadIdx.x;                  // feature group: 4t..4t+3
  int start = offsets[node], end = offsets[node + 1];
  float a0 = 0.f, a1 = 0.f, a2 = 0.f, a3 = 0.f;
  int i = start;
  for (; i + 4 <= end; i += 4) {
    int s0 = edge_src[i], s1 = edge_src[i + 1], s2 = edge_src[i + 2], s3 = edge_src[i + 3];
    short4v v0 = *(const short4v*)&xsb[(size_t)s0 * D + t * 4];
    short4v v1 = *(const short4v*)&xsb[(size_t)s1 * D + t * 4];
    short4v v2 = *(const short4v*)&xsb[(size_t)s2 * D + t * 4];
    short4v v3 = *(const short4v*)&xsb[(size_t)s3 * D + t * 4];
    a0 += bf2f((unsigned short)v0[0]) + bf2f((unsigned short)v1[0]) + bf2f((unsigned short)v2[0]) + bf2f((unsigned short)v3[0]);
    a1 += bf2f((unsigned short)v0[1]) + bf2f((unsigned short)v1[1]) + bf2f((unsigned short)v2[1]) + bf2f((unsigned short)v3[1]);
    a2 += bf2f((unsigned short)v0[2]) + bf2f((unsigned short)v1[2]) + bf2f((unsigned short)v2[2]) + bf2f((unsigned short)v3[2]);
    a3 += bf2f((unsigned short)v0[3]) + bf2f((unsigned short)v1[3]) + bf2f((unsigned short)v2[3]) + bf2f((unsigned short)v3[3]);
  }
  for (; i < end; ++i) {
    short4v v = *(const short4v*)&xsb[(size_t)edge_src[i] * D + t * 4];
    a0 += bf2f((unsigned short)v[0]); a1 += bf2f((unsigned short)v[1]);
    a2 += bf2f((unsigned short)v[2]); a3 += bf2f((unsigned short)v[3]);
  }
  int deg = end - start;
  float inv = 1.f / (float)(deg > 0 ? deg : 1);
  short4v r;
  r[0] = (short)f2bf(a0 * inv); r[1] = (short)f2bf(a1 * inv);
  r[2] = (short)f2bf(a2 * inv); r[3] = (short)f2bf(a3 * inv);
  *(short4v*)&aggr[(size_t)node * D + t * 4] = r;
}

// ---- f32 fallback aggr (aggr lives in d_out) ----------------------------
__global__ void aggr_f32_kernel(const float* __restrict__ xsrc, const int* __restrict__ offsets,
                                const int* __restrict__ edge_src, float* __restrict__ aggr) {
  int node = blockIdx.x;
  int t = threadIdx.x;
  int start = offsets[node], end = offsets[node + 1];
  float acc = 0.f;
  int i = start;
  for (; i + 4 <= end; i += 4) {
    int s0 = edge_src[i], s1 = edge_src[i + 1], s2 = edge_src[i + 2], s3 = edge_src[i + 3];
    acc += xsrc[(size_t)s0 * D + t];
    acc += xsrc[(size_t)s1 * D + t];
    acc += xsrc[(size_t)s2 * D + t];
    acc += xsrc[(size_t)s3 * D + t];
  }
  for (; i < end; ++i) acc += xsrc[(size_t)edge_src[i] * D + t];
  int deg = end - start;
  aggr[(size_t)node * D + t] = acc / (float)(deg > 0 ? deg : 1);
}

// ---- fused GEMM: out[64][256] = [aggr|x_tgt]bf16 @ Wcat + b -------------
// A_lds[64][512] bf16 (64KB), XOR-swizzled 16B chunks: chunk' = chunk ^ (row&7)
template <bool AGGR_BF16>
__global__ __launch_bounds__(256) void gemm_kernel(const void* __restrict__ aggrp,
                                                   const float* __restrict__ xtgt,
                                                   const unsigned short* __restrict__ Wt,
                                                   const float* __restrict__ bias,
                                                   float* __restrict__ out, int n_tgt) {
  __shared__ __align__(16) unsigned short A_lds[64 * 512];
  int t = threadIdx.x;
  int mbase = blockIdx.x * 64;

  // stage aggr -> A_lds rows, k=0..255
#pragma unroll
  for (int it = 0; it < 8; ++it) {
    int chunk = it * 256 + t;           // 0..2047
    int r = chunk >> 5, c = chunk & 31;
    int node = mbase + r;
    short8 v = {0, 0, 0, 0, 0, 0, 0, 0};
    if (node < n_tgt) {
      if (AGGR_BF16) {
        v = *(const short8*)&((const unsigned short*)aggrp)[(size_t)node * D + c * 8];
      } else {
        const float* ap = (const float*)aggrp;
        floatx4 f0 = *(const floatx4*)&ap[(size_t)node * D + c * 8];
        floatx4 f1 = *(const floatx4*)&ap[(size_t)node * D + c * 8 + 4];
        v[0] = (short)f2bf(f0[0]); v[1] = (short)f2bf(f0[1]);
        v[2] = (short)f2bf(f0[2]); v[3] = (short)f2bf(f0[3]);
        v[4] = (short)f2bf(f1[0]); v[5] = (short)f2bf(f1[1]);
        v[6] = (short)f2bf(f1[2]); v[7] = (short)f2bf(f1[3]);
      }
    }
    int sc = c ^ (r & 7);
    *(short8*)&A_lds[r * 512 + sc * 8] = v;
  }
  // stage x_tgt (f32 -> bf16) -> A_lds rows, k=256..511
#pragma unroll
  for (int it = 0; it < 8; ++it) {
    int chunk = it * 256 + t;
    int r = chunk >> 5, c = chunk & 31;
    int node = mbase + r;
    floatx4 f0 = {0.f, 0.f, 0.f, 0.f}, f1 = {0.f, 0.f, 0.f, 0.f};
    if (node < n_tgt) {
      f0 = *(const floatx4*)&xtgt[(size_t)node * D + c * 8];
      f1 = *(const floatx4*)&xtgt[(size_t)node * D + c * 8 + 4];
    }
    short8 v;
    v[0] = (short)f2bf(f0[0]); v[1] = (short)f2bf(f0[1]);
    v[2] = (short)f2bf(f0[2]); v[3] = (short)f2bf(f0[3]);
    v[4] = (short)f2bf(f1[0]); v[5] = (short)f2bf(f1[1]);
    v[6] = (short)f2bf(f1[2]); v[7] = (short)f2bf(f1[3]);
    int sc = (32 + c) ^ (r & 7);
    *(short8*)&A_lds[r * 512 + sc * 8] = v;
  }
  __syncthreads();

  int lane = t & 63, w = t >> 6;
  int lr = lane & 15, lq = lane >> 4;

  floatx4 acc[4][4];
#pragma unroll
  for (int mt = 0; mt < 4; ++mt)
#pragma unroll
    for (int nt = 0; nt < 4; ++nt) acc[mt][nt] = (floatx4){0.f, 0.f, 0.f, 0.f};

  const unsigned short* WtW = Wt + ((size_t)(64 * w + lr)) * 512 + lq * 8;

#pragma unroll
  for (int ks = 0; ks < 16; ++ks) {
    short8 a[4], b[4];
#pragma unroll
    for (int mt = 0; mt < 4; ++mt) {
      int row = 16 * mt + lr;
      int chunk = (ks * 4 + lq) ^ (row & 7);
      a[mt] = *(const short8*)&A_lds[row * 512 + chunk * 8];
    }
#pragma unroll
    for (int nt = 0; nt < 4; ++nt)
      b[nt] = *(const short8*)&WtW[(size_t)nt * 16 * 512 + ks * 32];
#pragma unroll
    for (int mt = 0; mt < 4; ++mt)
#pragma unroll
      for (int nt = 0; nt < 4; ++nt)
        acc[mt][nt] = __builtin_amdgcn_mfma_f32_16x16x32_bf16(a[mt], b[nt], acc[mt][nt], 0, 0, 0);
  }

  // epilogue: row=(lane>>4)*4+reg, col=lane&15
#pragma unroll
  for (int nt = 0; nt < 4; ++nt) {
    int oc = 64 * w + 16 * nt + lr;
    float bv = bias[oc];
#pragma unroll
    for (int mt = 0; mt < 4; ++mt) {
#pragma unroll
      for (int r4 = 0; r4 < 4; ++r4) {
        int node = mbase + 16 * mt + lq * 4 + r4;
        if (node < n_tgt) out[(size_t)node * D + oc] = acc[mt][nt][r4] + bv;
      }
    }
  }
}

extern "C" void kernel_launch(void* const* d_in, const int* in_sizes, int n_in,
                              void* d_out, int out_size, void* d_ws, size_t ws_size,
                              hipStream_t stream) {
  const float* x_src = (const float*)d_in[0];
  const float* x_tgt = (const float*)d_in[1];
  const void* ei = d_in[2];
  const float* W_l = (const float*)d_in[3];
  const float* b_l = (const float*)d_in[4];
  const float* W_r = (const float*)d_in[5];
  float* out = (float*)d_out;

  const int N_s = in_sizes[0] / D;     // source nodes
  const int N_t = in_sizes[1] / D;     // target nodes
  const int E = in_sizes[2] / 2;       // edges

  char* ws = (char*)d_ws;
  size_t o = 0;
  auto alloc = [&](size_t bytes) { size_t cur = o; o = (o + bytes + 255) & ~(size_t)255; return cur; };
  int* flag              = (int*)(ws + alloc(4));
  int* counts            = (int*)(ws + alloc((size_t)N_t * 4));
  int* offsets           = (int*)(ws + alloc(((size_t)N_t + 1) * 4));
  int* cursor            = (int*)(ws + alloc((size_t)N_t * 4));
  size_t zero_end        = o;
  int SB = (N_t + 1023) / 1024;
  int* bsum              = (int*)(ws + alloc(((size_t)SB) * 4));
  int* boff              = (int*)(ws + alloc(((size_t)SB + 1) * 4));
  int* edge_src          = (int*)(ws + alloc((size_t)E * 4));
  unsigned short* Wt     = (unsigned short*)(ws + alloc((size_t)256 * 512 * 2));
  size_t base_end        = o;
  unsigned short* xsrc_b = (unsigned short*)(ws + alloc((size_t)N_s * D * 2));
  unsigned short* aggr_b = (unsigned short*)(ws + alloc((size_t)N_t * D * 2));
  size_t bf16_end        = o;

  bool bf16_path = (ws_size >= bf16_end);
  (void)base_end;

  hipMemsetAsync(ws, 0, zero_end, stream);

  int eb = (E + 255) / 256;
  detect_kernel<<<1, 64, 0, stream>>>((const int*)ei, flag);
  count_kernel<<<eb, 256, 0, stream>>>(ei, flag, counts, E, N_t);
  scan_blocksum_kernel<<<SB, 256, 0, stream>>>(counts, bsum, N_t);
  scan_kernel<<<1, 1024, 0, stream>>>(bsum, boff, SB);
  scan_apply_kernel<<<SB, 256, 0, stream>>>(counts, boff, offsets, N_t);
  fill_kernel<<<eb, 256, 0, stream>>>(ei, flag, offsets, cursor, edge_src, E, N_t);
  wt_kernel<<<512, 256, 0, stream>>>(W_l, W_r, Wt);

  if (bf16_path) {
    long long n8 = (long long)N_s * D / 8;
    xcast_kernel<<<(int)((n8 + 255) / 256), 256, 0, stream>>>(x_src, xsrc_b, n8);
    aggr_bf_kernel<<<N_t, 64, 0, stream>>>(xsrc_b, offsets, edge_src, aggr_b);
    gemm_kernel<true><<<(N_t + 63) / 64, 256, 0, stream>>>(aggr_b, x_tgt, Wt, b_l, out, N_t);
  } else {
    aggr_f32_kernel<<<N_t, 256, 0, stream>>>(x_src, offsets, edge_src, out);
    gemm_kernel<false><<<(N_t + 63) / 64, 256, 0, stream>>>(out, x_tgt, Wt, b_l, out, N_t);
  }
}